// Round 2
// baseline (950.885 us; speedup 1.0000x reference)
//
#include <hip/hip_runtime.h>
#include <hip/hip_bf16.h>
#include <stdint.h>

typedef unsigned short u16;
typedef __attribute__((ext_vector_type(8))) short short8;
typedef __attribute__((ext_vector_type(4))) float float4v;
typedef __attribute__((ext_vector_type(4))) unsigned int uint4v;

#define B_    2
#define N_    2048
#define DIM_  1024
#define H_    16
#define DH_   64
#define DI_   1024
#define EPS_  1.1920928955078125e-07f
#define LOG2_THETA 13.287712379549449f

__device__ __forceinline__ float bf2f(u16 u) {
    union { unsigned int i; float f; } v; v.i = ((unsigned int)u) << 16; return v.f;
}
__device__ __forceinline__ u16 f2bf(float f) {
    union { float f; unsigned int i; } v; v.f = f;
    unsigned int r = v.i + 0x7fff + ((v.i >> 16) & 1);
    return (u16)(r >> 16);
}

// ---------------- RMSNorm over DIM for fp32 tokens -> bf16 Xn ----------------
__global__ __launch_bounds__(256) void k_rmsnorm_x(
    const float* __restrict__ tok, const float* __restrict__ w, u16* __restrict__ xn) {
    int row = blockIdx.x;                   // 0..B*N-1
    int t = threadIdx.x;                    // 256
    const float* tr = tok + (size_t)row * DIM_;
    float vals[4];
    float ss = 0.f;
#pragma unroll
    for (int i = 0; i < 4; ++i) {
        float v = tr[t + i * 256];
        vals[i] = v; ss += v * v;
    }
#pragma unroll
    for (int o = 32; o; o >>= 1) ss += __shfl_xor(ss, o, 64);
    __shared__ float red[4];
    if ((t & 63) == 0) red[t >> 6] = ss;
    __syncthreads();
    ss = red[0] + red[1] + red[2] + red[3];
    float rs = rsqrtf(ss * (1.0f / DIM_) + EPS_);
    u16* orow = xn + (size_t)row * DIM_;
#pragma unroll
    for (int i = 0; i < 4; ++i) {
        int c = t + i * 256;
        orow[c] = f2bf(vals[i] * rs * w[c]);
    }
}

// ---------------- weight transpose (K x N fp32) -> (N x K bf16) ----------------
__global__ __launch_bounds__(256) void k_transpose(
    const float* __restrict__ src, u16* __restrict__ dst, int K, int N) {
    __shared__ float tile[32][33];
    int n0 = blockIdx.x * 32, k0 = blockIdx.y * 32;
    int tx = threadIdx.x, ty = threadIdx.y;  // 32 x 8
#pragma unroll
    for (int i = 0; i < 4; ++i)
        tile[ty + 8 * i][tx] = src[(size_t)(k0 + ty + 8 * i) * N + n0 + tx];
    __syncthreads();
#pragma unroll
    for (int i = 0; i < 4; ++i)
        dst[(size_t)(n0 + ty + 8 * i) * K + k0 + tx] = f2bf(tile[tx][ty + 8 * i]);
}

// ---------------- GEMM: C[MxN] = A[MxK] * Bt[NxK]^T  (m97 structure) ----------------
template <bool OUT_F32>
__global__ __launch_bounds__(256) void k_gemm_bt(
    const u16* __restrict__ A, const u16* __restrict__ Bt, void* __restrict__ Cv,
    int K, int Ncols) {
    __shared__ u16 As[128 * 32];
    __shared__ u16 Bs[128 * 32];
    int m0 = blockIdx.x * 128, n0 = blockIdx.y * 128;
    int t = threadIdx.x;
    int w = t >> 6, lane = t & 63, ln = lane & 15, quad = lane >> 4;
    int wm = w & 1, wn = w >> 1;
    float4v acc[4][4] = {};
    const u16* Ag = A + (size_t)m0 * K;
    const u16* Bg = Bt + (size_t)n0 * K;
    for (int k0 = 0; k0 < K; k0 += 32) {
        __syncthreads();
#pragma unroll
        for (int i = 0; i < 2; ++i) {
            int idx = i * 256 + t;          // 0..511 : row=idx/4, 16B chunk=idx%4
            int row = idx >> 2, kb = idx & 3;
            const u16* ga = Ag + (size_t)row * K + k0 + kb * 8;
            const u16* gb = Bg + (size_t)row * K + k0 + kb * 8;
            __builtin_amdgcn_global_load_lds(
                (const __attribute__((address_space(1))) void*)ga,
                (__attribute__((address_space(3))) void*)(As + idx * 8), 16, 0, 0);
            __builtin_amdgcn_global_load_lds(
                (const __attribute__((address_space(1))) void*)gb,
                (__attribute__((address_space(3))) void*)(Bs + idx * 8), 16, 0, 0);
        }
        asm volatile("s_waitcnt vmcnt(0)" ::: "memory");
        __syncthreads();
        short8 af[4], bfr[4];
#pragma unroll
        for (int mt = 0; mt < 4; ++mt)
            af[mt] = *(const short8*)(As + (wm * 64 + mt * 16 + ln) * 32 + quad * 8);
#pragma unroll
        for (int nt = 0; nt < 4; ++nt)
            bfr[nt] = *(const short8*)(Bs + (wn * 64 + nt * 16 + ln) * 32 + quad * 8);
#pragma unroll
        for (int mt = 0; mt < 4; ++mt)
#pragma unroll
            for (int nt = 0; nt < 4; ++nt)
                acc[mt][nt] = __builtin_amdgcn_mfma_f32_16x16x32_bf16(
                    af[mt], bfr[nt], acc[mt][nt], 0, 0, 0);
    }
#pragma unroll
    for (int mt = 0; mt < 4; ++mt)
#pragma unroll
        for (int nt = 0; nt < 4; ++nt)
#pragma unroll
            for (int r = 0; r < 4; ++r) {
                int row = m0 + wm * 64 + mt * 16 + quad * 4 + r;
                int col = n0 + wn * 64 + nt * 16 + ln;
                if (OUT_F32)
                    ((float*)Cv)[(size_t)row * Ncols + col] = acc[mt][nt][r];
                else
                    ((u16*)Cv)[(size_t)row * Ncols + col] = f2bf(acc[mt][nt][r]);
            }
}

// ---------------- in-place RoPE on token-major [B*N][H*DH] (bf16) ----------------
__global__ __launch_bounds__(256) void k_rope(u16* __restrict__ buf) {
    int vid = blockIdx.x * 4 + (threadIdx.x >> 6);   // (b*N+n)*H + h
    int lane = threadIdx.x & 63;
    int h = vid & (H_ - 1);
    int row = vid >> 4;                              // b*N + n
    int n = row & (N_ - 1);
    u16* p = buf + (size_t)row * DI_ + h * 64;
    float x = bf2f(p[lane]);
    float partner = __shfl_xor(x, 1, 64);
    float inv = exp2f(-(float)(lane & ~1) * (LOG2_THETA / 64.0f));
    float fr = (float)n * inv;
    float sv, cv;
    sincosf(fr, &sv, &cv);
    float out = x * cv + ((lane & 1) ? partner : -partner) * sv;
    p[lane] = f2bf(out);
}

// ---------------- in-place RMSNorm(DH) + RoPE on K buffers (bf16, fp32 w) ----------------
__global__ __launch_bounds__(256) void k_rms_rope_k(
    u16* __restrict__ buf, const float* __restrict__ w, int nsets) {
    int vid = blockIdx.x * 4 + (threadIdx.x >> 6);
    int lane = threadIdx.x & 63;
    int h = vid % H_;
    int s = (vid / H_) % nsets;
    int row = vid / (H_ * nsets);                    // b*N + n
    int n = row & (N_ - 1);
    u16* p = buf + (size_t)row * (size_t)(nsets * DI_) + s * DI_ + h * 64;
    float x = bf2f(p[lane]);
    float ss = x * x;
#pragma unroll
    for (int o = 32; o; o >>= 1) ss += __shfl_xor(ss, o, 64);
    float rs = rsqrtf(ss * (1.0f / 64.0f) + EPS_);
    float xn = x * rs * w[s * 64 + lane];
    float partner = __shfl_xor(xn, 1, 64);
    float inv = exp2f(-(float)(lane & ~1) * (LOG2_THETA / 64.0f));
    float fr = (float)n * inv;
    float sv, cv;
    sincosf(fr, &sv, &cv);
    float out = xn * cv + ((lane & 1) ? partner : -partner) * sv;
    p[lane] = f2bf(out);
}

// ---------------- flash attention (causal, online softmax) ----------------
__global__ __launch_bounds__(256) void k_flash(
    const u16* __restrict__ Q, const u16* __restrict__ K, const u16* __restrict__ V,
    u16* __restrict__ O, int kv_stride, int set_off, size_t o_set_stride) {
    int qt = blockIdx.x;
    int bh = blockIdx.y;
    int s = blockIdx.z;
    int b = bh >> 4, h = bh & 15;
    int t = threadIdx.x;
    int w = t >> 6, lane = t & 63, ln = lane & 15, quad = lane >> 4;
    int q0 = qt * 64;

    const u16* Qb = Q + ((size_t)b * N_) * DI_ + h * 64;
    const u16* Kb = K + ((size_t)b * N_) * kv_stride + (size_t)s * set_off + h * 64;
    const u16* Vb = V + ((size_t)b * N_) * kv_stride + (size_t)s * set_off + h * 64;
    u16* Ob = O + (size_t)s * o_set_stride + ((size_t)b * N_) * DI_ + h * 64;

    __shared__ u16 Ks[64][72];
    __shared__ u16 Vs[64][72];     // transposed: Vs[d][n]
    __shared__ u16 Ps[4][16][72];  // per-wave P staging

    int qg = q0 + w * 16 + ln;
    short8 qf[2];
#pragma unroll
    for (int dh = 0; dh < 2; ++dh)
        qf[dh] = *(const short8*)(Qb + (size_t)qg * DI_ + dh * 32 + quad * 8);

    float m_i[4], l_i[4];
    float4v accO[4] = {};
#pragma unroll
    for (int r = 0; r < 4; ++r) { m_i[r] = -1e30f; l_i[r] = 0.f; }

    int ntiles = qt + 1;
    for (int kt0 = 0; kt0 < ntiles; ++kt0) {
        int k0 = kt0 * 64;
        __syncthreads();
#pragma unroll
        for (int i = 0; i < 2; ++i) {
            int idx = i * 256 + t;           // 0..511
            int row = idx >> 3;
            int db = (idx & 7) * 8;
            uint4v kv = *(const uint4v*)(Kb + (size_t)(k0 + row) * kv_stride + db);
            *(uint4v*)&Ks[row][db] = kv;
            uint4v vv = *(const uint4v*)(Vb + (size_t)(k0 + row) * kv_stride + db);
            union { uint4v v; u16 u[8]; } cc; cc.v = vv;
#pragma unroll
            for (int j = 0; j < 8; ++j) Vs[db + j][row] = cc.u[j];
        }
        __syncthreads();

        // S = Q K^T (per wave: 16 q-rows x 64 keys)
        float sv[4][4];
#pragma unroll
        for (int kt = 0; kt < 4; ++kt) {
            short8 kf0 = *(const short8*)&Ks[kt * 16 + ln][quad * 8];
            short8 kf1 = *(const short8*)&Ks[kt * 16 + ln][32 + quad * 8];
            float4v sa = {};
            sa = __builtin_amdgcn_mfma_f32_16x16x32_bf16(qf[0], kf0, sa, 0, 0, 0);
            sa = __builtin_amdgcn_mfma_f32_16x16x32_bf16(qf[1], kf1, sa, 0, 0, 0);
            int kg = k0 + kt * 16 + ln;
#pragma unroll
            for (int r = 0; r < 4; ++r) {
                int qr = q0 + w * 16 + quad * 4 + r;
                sv[kt][r] = (kg <= qr) ? sa[r] * 0.125f : -1e30f;
            }
        }

        // online softmax update
#pragma unroll
        for (int r = 0; r < 4; ++r) {
            float mx = fmaxf(fmaxf(sv[0][r], sv[1][r]), fmaxf(sv[2][r], sv[3][r]));
#pragma unroll
            for (int o = 1; o < 16; o <<= 1) mx = fmaxf(mx, __shfl_xor(mx, o, 64));
            float mnew = fmaxf(m_i[r], mx);
            float alpha = __expf(m_i[r] - mnew);
            float psum = 0.f;
#pragma unroll
            for (int kt = 0; kt < 4; ++kt) {
                float pv = __expf(sv[kt][r] - mnew);
                sv[kt][r] = pv;
                psum += pv;
            }
#pragma unroll
            for (int o = 1; o < 16; o <<= 1) psum += __shfl_xor(psum, o, 64);
            l_i[r] = l_i[r] * alpha + psum;
            m_i[r] = mnew;
#pragma unroll
            for (int dc = 0; dc < 4; ++dc) accO[dc][r] *= alpha;
        }

        // P: C/D layout -> A-operand layout via LDS
#pragma unroll
        for (int kt = 0; kt < 4; ++kt)
#pragma unroll
            for (int r = 0; r < 4; ++r)
                Ps[w][quad * 4 + r][kt * 16 + ln] = f2bf(sv[kt][r]);
        __syncthreads();

        short8 pf[2];
#pragma unroll
        for (int nt = 0; nt < 2; ++nt)
            pf[nt] = *(const short8*)&Ps[w][ln][nt * 32 + quad * 8];
#pragma unroll
        for (int dc = 0; dc < 4; ++dc)
#pragma unroll
            for (int nt = 0; nt < 2; ++nt) {
                short8 vf = *(const short8*)&Vs[dc * 16 + ln][nt * 32 + quad * 8];
                accO[dc] = __builtin_amdgcn_mfma_f32_16x16x32_bf16(pf[nt], vf, accO[dc], 0, 0, 0);
            }
    }

#pragma unroll
    for (int dc = 0; dc < 4; ++dc)
#pragma unroll
        for (int r = 0; r < 4; ++r) {
            int qr = q0 + w * 16 + quad * 4 + r;
            float ov = accO[dc][r] / l_i[r];
            Ob[(size_t)qr * DI_ + dc * 16 + ln] = f2bf(ov);
        }
}

extern "C" void kernel_launch(void* const* d_in, const int* in_sizes, int n_in,
                              void* d_out, int out_size, void* d_ws, size_t ws_size,
                              hipStream_t stream) {
    const float* tok     = (const float*)d_in[0];
    const float* w_norm  = (const float*)d_in[1];
    const float* w_q     = (const float*)d_in[2];
    const float* w_k     = (const float*)d_in[3];
    const float* w_v     = (const float*)d_in[4];
    const float* w_keyn  = (const float*)d_in[5];
    const float* w_nestk = (const float*)d_in[6];
    const float* w_o     = (const float*)d_in[7];

    char* ws = (char*)d_ws;
    const size_t MB = 1024 * 1024;
    u16* XN   = (u16*)(ws + 0 * MB);     // 4096x1024 bf16
    u16* QB   = (u16*)(ws + 8 * MB);     // 4096x1024
    u16* KB   = (u16*)(ws + 16 * MB);    // 4096x3072
    u16* VB   = (u16*)(ws + 40 * MB);    // 4096x3072
    u16* NQKV = (u16*)(ws + 64 * MB);    // 3 x 4096x1024
    u16* OUT2 = (u16*)(ws + 88 * MB);    // 4096x1024
    u16* WQT  = (u16*)(ws + 96 * MB);    // 1024x1024
    u16* WKT  = (u16*)(ws + 98 * MB);    // 3072x1024
    u16* WVT  = (u16*)(ws + 104 * MB);   // 3072x1024
    u16* WOT  = (u16*)(ws + 110 * MB);   // 1024x1024

    const size_t SET = (size_t)B_ * N_ * DI_;  // 4096*1024

    k_transpose<<<dim3(32, 32), dim3(32, 8), 0, stream>>>(w_q, WQT, 1024, 1024);
    k_transpose<<<dim3(96, 32), dim3(32, 8), 0, stream>>>(w_k, WKT, 1024, 3072);
    k_transpose<<<dim3(96, 32), dim3(32, 8), 0, stream>>>(w_v, WVT, 1024, 3072);
    k_transpose<<<dim3(32, 32), dim3(32, 8), 0, stream>>>(w_o, WOT, 1024, 1024);

    k_rmsnorm_x<<<B_ * N_, 256, 0, stream>>>(tok, w_norm, XN);

    k_gemm_bt<false><<<dim3(32, 8),  256, 0, stream>>>(XN, WQT, QB, 1024, 1024);
    k_gemm_bt<false><<<dim3(32, 24), 256, 0, stream>>>(XN, WKT, KB, 1024, 3072);
    k_gemm_bt<false><<<dim3(32, 24), 256, 0, stream>>>(XN, WVT, VB, 1024, 3072);

    k_rope<<<(B_ * N_ * H_) / 4, 256, 0, stream>>>(QB);
    k_rms_rope_k<<<(B_ * N_ * 3 * H_) / 4, 256, 0, stream>>>(KB, w_keyn, 3);

    k_flash<<<dim3(N_ / 64, B_ * H_, 3), 256, 0, stream>>>(
        QB, KB, VB, NQKV, 3 * DI_, DI_, SET);

    k_rope<<<(B_ * N_ * H_) / 4, 256, 0, stream>>>(NQKV);
    k_rms_rope_k<<<(B_ * N_ * H_) / 4, 256, 0, stream>>>(NQKV + SET, w_nestk, 1);

    k_flash<<<dim3(N_ / 64, B_ * H_, 1), 256, 0, stream>>>(
        NQKV, NQKV + SET, NQKV + 2 * SET, OUT2, DI_, 0, 0);

    k_gemm_bt<true><<<dim3(32, 8), 256, 0, stream>>>(OUT2, WOT, (float*)d_out, 1024, 1024);
}

// Round 3
// 813.402 us; speedup vs baseline: 1.1690x; 1.1690x over previous
//
#include <hip/hip_runtime.h>
#include <hip/hip_bf16.h>
#include <stdint.h>

typedef unsigned short u16;
typedef __attribute__((ext_vector_type(8))) short short8;
typedef __attribute__((ext_vector_type(4))) float float4v;
typedef __attribute__((ext_vector_type(4))) unsigned int uint4v;

#define B_    2
#define N_    2048
#define DIM_  1024
#define H_    16
#define DH_   64
#define DI_   1024
#define EPS_  1.1920928955078125e-07f
#define LOG2_THETA 13.287712379549449f
#define SCL_  0.18033688011112042f   // (1/sqrt(64)) * log2(e)

__device__ __forceinline__ float bf2f(u16 u) {
    union { unsigned int i; float f; } v; v.i = ((unsigned int)u) << 16; return v.f;
}
__device__ __forceinline__ u16 f2bf(float f) {
    union { float f; unsigned int i; } v; v.f = f;
    unsigned int r = v.i + 0x7fff + ((v.i >> 16) & 1);
    return (u16)(r >> 16);
}

// ---------------- RMSNorm over DIM for fp32 tokens -> bf16 Xn ----------------
__global__ __launch_bounds__(256) void k_rmsnorm_x(
    const float* __restrict__ tok, const float* __restrict__ w, u16* __restrict__ xn) {
    int row = blockIdx.x;
    int t = threadIdx.x;
    const float* tr = tok + (size_t)row * DIM_;
    float vals[4];
    float ss = 0.f;
#pragma unroll
    for (int i = 0; i < 4; ++i) {
        float v = tr[t + i * 256];
        vals[i] = v; ss += v * v;
    }
#pragma unroll
    for (int o = 32; o; o >>= 1) ss += __shfl_xor(ss, o, 64);
    __shared__ float red[4];
    if ((t & 63) == 0) red[t >> 6] = ss;
    __syncthreads();
    ss = red[0] + red[1] + red[2] + red[3];
    float rs = rsqrtf(ss * (1.0f / DIM_) + EPS_);
    u16* orow = xn + (size_t)row * DIM_;
#pragma unroll
    for (int i = 0; i < 4; ++i) {
        int c = t + i * 256;
        orow[c] = f2bf(vals[i] * rs * w[c]);
    }
}

// ---------------- weight transpose (K x N fp32) -> (N x K bf16) ----------------
__global__ __launch_bounds__(256) void k_transpose(
    const float* __restrict__ src, u16* __restrict__ dst, int K, int N) {
    __shared__ float tile[32][33];
    int n0 = blockIdx.x * 32, k0 = blockIdx.y * 32;
    int tx = threadIdx.x, ty = threadIdx.y;  // 32 x 8
#pragma unroll
    for (int i = 0; i < 4; ++i)
        tile[ty + 8 * i][tx] = src[(size_t)(k0 + ty + 8 * i) * N + n0 + tx];
    __syncthreads();
#pragma unroll
    for (int i = 0; i < 4; ++i)
        dst[(size_t)(n0 + ty + 8 * i) * K + k0 + tx] = f2bf(tile[tx][ty + 8 * i]);
}

// ------- V transpose: VB token-major [B*N][3*1024] -> Vt [(s*B+b)*H+h][64][N] -------
__global__ __launch_bounds__(256) void k_transpose_v(
    const u16* __restrict__ VB, u16* __restrict__ Vt) {
    int y = blockIdx.y;                 // (s*B_+b)*H_+h
    int s = y >> 5;
    int b = (y >> 4) & 1;
    int h = y & 15;
    int n0 = blockIdx.x * 64;
    __shared__ u16 tile[64][72];
    int t = threadIdx.x;
#pragma unroll
    for (int i = 0; i < 2; ++i) {
        int idx = i * 256 + t;
        int row = idx >> 3, c = idx & 7;   // row = token offset, c = dh chunk
        uint4v v = *(const uint4v*)(VB + ((size_t)(b * N_) + n0 + row) * 3072
                                        + s * 1024 + h * 64 + c * 8);
        *(uint4v*)&tile[row][c * 8] = v;
    }
    __syncthreads();
    u16* out = Vt + (size_t)y * 64 * N_;
#pragma unroll
    for (int i = 0; i < 2; ++i) {
        int idx = i * 256 + t;
        int dh = idx >> 3, c = idx & 7;
        union { uint4v v; u16 u[8]; } o;
#pragma unroll
        for (int j = 0; j < 8; ++j) o.u[j] = tile[c * 8 + j][dh];
        *(uint4v*)(out + (size_t)dh * N_ + n0 + c * 8) = o.v;
    }
}

// ---------------- GEMM: C[MxN] = A[MxK] * Bt[NxK]^T  (m97 structure) ----------------
template <bool OUT_F32>
__global__ __launch_bounds__(256) void k_gemm_bt(
    const u16* __restrict__ A, const u16* __restrict__ Bt, void* __restrict__ Cv,
    int K, int Ncols) {
    __shared__ u16 As[128 * 32];
    __shared__ u16 Bs[128 * 32];
    int m0 = blockIdx.x * 128, n0 = blockIdx.y * 128;
    int t = threadIdx.x;
    int w = t >> 6, lane = t & 63, ln = lane & 15, quad = lane >> 4;
    int wm = w & 1, wn = w >> 1;
    float4v acc[4][4] = {};
    const u16* Ag = A + (size_t)m0 * K;
    const u16* Bg = Bt + (size_t)n0 * K;
    for (int k0 = 0; k0 < K; k0 += 32) {
        __syncthreads();
#pragma unroll
        for (int i = 0; i < 2; ++i) {
            int idx = i * 256 + t;
            int row = idx >> 2, kb = idx & 3;
            const u16* ga = Ag + (size_t)row * K + k0 + kb * 8;
            const u16* gb = Bg + (size_t)row * K + k0 + kb * 8;
            __builtin_amdgcn_global_load_lds(
                (const __attribute__((address_space(1))) void*)ga,
                (__attribute__((address_space(3))) void*)(As + idx * 8), 16, 0, 0);
            __builtin_amdgcn_global_load_lds(
                (const __attribute__((address_space(1))) void*)gb,
                (__attribute__((address_space(3))) void*)(Bs + idx * 8), 16, 0, 0);
        }
        asm volatile("s_waitcnt vmcnt(0)" ::: "memory");
        __syncthreads();
        short8 af[4], bfr[4];
#pragma unroll
        for (int mt = 0; mt < 4; ++mt)
            af[mt] = *(const short8*)(As + (wm * 64 + mt * 16 + ln) * 32 + quad * 8);
#pragma unroll
        for (int nt = 0; nt < 4; ++nt)
            bfr[nt] = *(const short8*)(Bs + (wn * 64 + nt * 16 + ln) * 32 + quad * 8);
#pragma unroll
        for (int mt = 0; mt < 4; ++mt)
#pragma unroll
            for (int nt = 0; nt < 4; ++nt)
                acc[mt][nt] = __builtin_amdgcn_mfma_f32_16x16x32_bf16(
                    af[mt], bfr[nt], acc[mt][nt], 0, 0, 0);
    }
#pragma unroll
    for (int mt = 0; mt < 4; ++mt)
#pragma unroll
        for (int nt = 0; nt < 4; ++nt)
#pragma unroll
            for (int r = 0; r < 4; ++r) {
                int row = m0 + wm * 64 + mt * 16 + quad * 4 + r;
                int col = n0 + wn * 64 + nt * 16 + ln;
                if (OUT_F32)
                    ((float*)Cv)[(size_t)row * Ncols + col] = acc[mt][nt][r];
                else
                    ((u16*)Cv)[(size_t)row * Ncols + col] = f2bf(acc[mt][nt][r]);
            }
}

// ---------------- in-place RoPE on token-major [B*N][H*DH] (bf16) ----------------
__global__ __launch_bounds__(256) void k_rope(u16* __restrict__ buf) {
    int vid = blockIdx.x * 4 + (threadIdx.x >> 6);
    int lane = threadIdx.x & 63;
    int h = vid & (H_ - 1);
    int row = vid >> 4;
    int n = row & (N_ - 1);
    u16* p = buf + (size_t)row * DI_ + h * 64;
    float x = bf2f(p[lane]);
    float partner = __shfl_xor(x, 1, 64);
    float inv = exp2f(-(float)(lane & ~1) * (LOG2_THETA / 64.0f));
    float fr = (float)n * inv;
    float sv, cv;
    sincosf(fr, &sv, &cv);
    float out = x * cv + ((lane & 1) ? partner : -partner) * sv;
    p[lane] = f2bf(out);
}

// ---------------- in-place RMSNorm(DH) + RoPE on K buffers (bf16, fp32 w) ----------------
__global__ __launch_bounds__(256) void k_rms_rope_k(
    u16* __restrict__ buf, const float* __restrict__ w, int nsets) {
    int vid = blockIdx.x * 4 + (threadIdx.x >> 6);
    int lane = threadIdx.x & 63;
    int h = vid % H_;
    int s = (vid / H_) % nsets;
    int row = vid / (H_ * nsets);
    int n = row & (N_ - 1);
    u16* p = buf + (size_t)row * (size_t)(nsets * DI_) + s * DI_ + h * 64;
    float x = bf2f(p[lane]);
    float ss = x * x;
#pragma unroll
    for (int o = 32; o; o >>= 1) ss += __shfl_xor(ss, o, 64);
    float rs = rsqrtf(ss * (1.0f / 64.0f) + EPS_);
    float xn = x * rs * w[s * 64 + lane];
    float partner = __shfl_xor(xn, 1, 64);
    float inv = exp2f(-(float)(lane & ~1) * (LOG2_THETA / 64.0f));
    float fr = (float)n * inv;
    float sv, cv;
    sincosf(fr, &sv, &cv);
    float out = xn * cv + ((lane & 1) ? partner : -partner) * sv;
    p[lane] = f2bf(out);
}

// ---------------- flash attention v2 (causal, online softmax, dbuf prefetch) ----------------
// Q token-major; K token-major (kv_stride, set_off); Vt pre-transposed [(s*B+b)*H+h][64][N].
// Output: token-major for s<2 (O + s*o_set_stride); set 2 writes transposed to Ot.
__global__ __launch_bounds__(256) void k_flash(
    const u16* __restrict__ Q, const u16* __restrict__ K, const u16* __restrict__ Vt,
    u16* __restrict__ O, u16* __restrict__ Ot,
    int kv_stride, int set_off, size_t o_set_stride) {
    int qt = blockIdx.x;
    int bh = blockIdx.y;
    int s = blockIdx.z;
    int b = bh >> 4, h = bh & 15;
    int t = threadIdx.x;
    int w = t >> 6, lane = t & 63, ln = lane & 15, quad = lane >> 4;
    int lnx = ln & 7;
    int q0 = qt * 64;

    const u16* Qb  = Q + ((size_t)b * N_) * DI_ + h * 64;
    const u16* Kb  = K + ((size_t)b * N_) * kv_stride + (size_t)s * set_off + h * 64;
    const u16* Vtb = Vt + (size_t)((s * B_ + b) * H_ + h) * (64 * (size_t)N_);

    // unpadded tiles, chunk-XOR swizzled: slot (row, c) holds global chunk (c ^ (row&7))
    __shared__ u16 Ks[2][64][64];
    __shared__ u16 Vs[2][64][64];
    __shared__ u16 Ps[4][16][72];

    int qg = q0 + w * 16 + ln;
    short8 qf[2];
#pragma unroll
    for (int f = 0; f < 2; ++f)
        qf[f] = *(const short8*)(Qb + (size_t)qg * DI_ + f * 32 + quad * 8);

    float m_i[4], l_i[4];
    float4v accO[4] = {};
#pragma unroll
    for (int r = 0; r < 4; ++r) { m_i[r] = -1e30f; l_i[r] = 0.f; }

    int ntiles = qt + 1;

    auto stage = [&](int kt0, int buf) {
        int k0 = kt0 * 64;
#pragma unroll
        for (int i = 0; i < 2; ++i) {
            int idx = i * 256 + t;
            int row = idx >> 3, c = idx & 7;
            int csrc = ((c ^ (row & 7)) * 8);
            const u16* ga = Kb + (size_t)(k0 + row) * kv_stride + csrc;
            __builtin_amdgcn_global_load_lds(
                (const __attribute__((address_space(1))) void*)ga,
                (__attribute__((address_space(3))) void*)&Ks[buf][row][c * 8], 16, 0, 0);
            const u16* gv = Vtb + (size_t)row * N_ + k0 + csrc;
            __builtin_amdgcn_global_load_lds(
                (const __attribute__((address_space(1))) void*)gv,
                (__attribute__((address_space(3))) void*)&Vs[buf][row][c * 8], 16, 0, 0);
        }
    };
    stage(0, 0);

    for (int kt0 = 0; kt0 < ntiles; ++kt0) {
        asm volatile("s_waitcnt vmcnt(0)" ::: "memory");
        __syncthreads();
        if (kt0 + 1 < ntiles) stage(kt0 + 1, (kt0 + 1) & 1);
        int buf = kt0 & 1;
        int k0 = kt0 * 64;

        // S = Q K^T (per wave: 16 q-rows x 64 keys), log2 domain
        float sv[4][4];
#pragma unroll
        for (int kt = 0; kt < 4; ++kt) {
            const u16* krow = &Ks[buf][kt * 16 + ln][0];
            short8 kf0 = *(const short8*)(krow + ((quad ^ lnx) * 8));
            short8 kf1 = *(const short8*)(krow + (((4 + quad) ^ lnx) * 8));
            float4v sa = {};
            sa = __builtin_amdgcn_mfma_f32_16x16x32_bf16(qf[0], kf0, sa, 0, 0, 0);
            sa = __builtin_amdgcn_mfma_f32_16x16x32_bf16(qf[1], kf1, sa, 0, 0, 0);
            int kg = k0 + kt * 16 + ln;
#pragma unroll
            for (int r = 0; r < 4; ++r) {
                int qr = q0 + w * 16 + quad * 4 + r;
                sv[kt][r] = (kg <= qr) ? sa[r] * SCL_ : -1e30f;
            }
        }

        // online softmax (base-2)
#pragma unroll
        for (int r = 0; r < 4; ++r) {
            float mx = fmaxf(fmaxf(sv[0][r], sv[1][r]), fmaxf(sv[2][r], sv[3][r]));
#pragma unroll
            for (int o = 1; o < 16; o <<= 1) mx = fmaxf(mx, __shfl_xor(mx, o, 64));
            float mnew = fmaxf(m_i[r], mx);
            float alpha = exp2f(m_i[r] - mnew);
            float psum = 0.f;
#pragma unroll
            for (int kt = 0; kt < 4; ++kt) {
                float pv = exp2f(sv[kt][r] - mnew);
                sv[kt][r] = pv;
                psum += pv;
            }
#pragma unroll
            for (int o = 1; o < 16; o <<= 1) psum += __shfl_xor(psum, o, 64);
            l_i[r] = l_i[r] * alpha + psum;
            m_i[r] = mnew;
#pragma unroll
            for (int dc = 0; dc < 4; ++dc) accO[dc][r] *= alpha;
        }

        // P: C/D layout -> A-operand layout via per-wave LDS (no block barrier needed)
#pragma unroll
        for (int kt = 0; kt < 4; ++kt)
#pragma unroll
            for (int r = 0; r < 4; ++r)
                Ps[w][quad * 4 + r][kt * 16 + ln] = f2bf(sv[kt][r]);
        asm volatile("s_waitcnt lgkmcnt(0)" ::: "memory");

        short8 pf0 = *(const short8*)&Ps[w][ln][quad * 8];
        short8 pf1 = *(const short8*)&Ps[w][ln][32 + quad * 8];
#pragma unroll
        for (int dc = 0; dc < 4; ++dc) {
            const u16* vrow = &Vs[buf][dc * 16 + ln][0];
            short8 vf0 = *(const short8*)(vrow + ((quad ^ lnx) * 8));
            short8 vf1 = *(const short8*)(vrow + (((4 + quad) ^ lnx) * 8));
            accO[dc] = __builtin_amdgcn_mfma_f32_16x16x32_bf16(pf0, vf0, accO[dc], 0, 0, 0);
            accO[dc] = __builtin_amdgcn_mfma_f32_16x16x32_bf16(pf1, vf1, accO[dc], 0, 0, 0);
        }
    }

    float rinv[4];
#pragma unroll
    for (int r = 0; r < 4; ++r) rinv[r] = 1.0f / l_i[r];

    if (s == 2) {
        // transposed output (this set is consumed as V by the next level)
        u16* Otb = Ot + (size_t)(b * H_ + h) * (64 * (size_t)N_);
#pragma unroll
        for (int dc = 0; dc < 4; ++dc)
#pragma unroll
            for (int r = 0; r < 4; ++r) {
                int qr = q0 + w * 16 + quad * 4 + r;
                Otb[(size_t)(dc * 16 + ln) * N_ + qr] = f2bf(accO[dc][r] * rinv[r]);
            }
    } else {
        u16* Ob = O + (size_t)s * o_set_stride + ((size_t)b * N_) * DI_ + h * 64;
#pragma unroll
        for (int dc = 0; dc < 4; ++dc)
#pragma unroll
            for (int r = 0; r < 4; ++r) {
                int qr = q0 + w * 16 + quad * 4 + r;
                Ob[(size_t)qr * DI_ + dc * 16 + ln] = f2bf(accO[dc][r] * rinv[r]);
            }
    }
}

extern "C" void kernel_launch(void* const* d_in, const int* in_sizes, int n_in,
                              void* d_out, int out_size, void* d_ws, size_t ws_size,
                              hipStream_t stream) {
    const float* tok     = (const float*)d_in[0];
    const float* w_norm  = (const float*)d_in[1];
    const float* w_q     = (const float*)d_in[2];
    const float* w_k     = (const float*)d_in[3];
    const float* w_v     = (const float*)d_in[4];
    const float* w_keyn  = (const float*)d_in[5];
    const float* w_nestk = (const float*)d_in[6];
    const float* w_o     = (const float*)d_in[7];

    char* ws = (char*)d_ws;
    const size_t MB = 1024 * 1024;
    // lifetime-overlapped layout (112 MB total):
    u16* XN   = (u16*)(ws + 0 * MB);     // phase 1 (rmsnorm -> QKV GEMMs)
    u16* QB   = (u16*)(ws + 8 * MB);
    u16* KB   = (u16*)(ws + 16 * MB);    // 24 MB
    u16* VB   = (u16*)(ws + 40 * MB);    // 24 MB, dead after k_transpose_v
    u16* OUT2 = (u16*)(ws + 40 * MB);    // reuses VB (written by flash L2)
    u16* VtB  = (u16*)(ws + 64 * MB);    // 24 MB
    u16* WQT  = (u16*)(ws + 64 * MB);    // weights overlap VtB (dead before transpose_v)
    u16* WKT  = (u16*)(ws + 66 * MB);
    u16* WVT  = (u16*)(ws + 72 * MB);
    u16* NQKV = (u16*)(ws + 88 * MB);    // sets 0,1 token-major (16 MB)
    u16* NVt  = (u16*)(ws + 104 * MB);   // set 2 transposed (8 MB)
    u16* WOT  = (u16*)(ws + 0 * MB);     // reuses XN (created late, read by final GEMM)

    const size_t SET = (size_t)B_ * N_ * DI_;

    k_transpose<<<dim3(32, 32), dim3(32, 8), 0, stream>>>(w_q, WQT, 1024, 1024);
    k_transpose<<<dim3(96, 32), dim3(32, 8), 0, stream>>>(w_k, WKT, 1024, 3072);
    k_transpose<<<dim3(96, 32), dim3(32, 8), 0, stream>>>(w_v, WVT, 1024, 3072);

    k_rmsnorm_x<<<B_ * N_, 256, 0, stream>>>(tok, w_norm, XN);

    k_gemm_bt<false><<<dim3(32, 8),  256, 0, stream>>>(XN, WQT, QB, 1024, 1024);
    k_gemm_bt<false><<<dim3(32, 24), 256, 0, stream>>>(XN, WKT, KB, 1024, 3072);
    k_gemm_bt<false><<<dim3(32, 24), 256, 0, stream>>>(XN, WVT, VB, 1024, 3072);

    k_transpose_v<<<dim3(N_ / 64, 3 * B_ * H_), 256, 0, stream>>>(VB, VtB);

    k_rope<<<(B_ * N_ * H_) / 4, 256, 0, stream>>>(QB);
    k_rms_rope_k<<<(B_ * N_ * 3 * H_) / 4, 256, 0, stream>>>(KB, w_keyn, 3);

    k_flash<<<dim3(N_ / 64, B_ * H_, 3), 256, 0, stream>>>(
        QB, KB, VtB, NQKV, NVt, 3 * DI_, DI_, SET);

    k_rope<<<(B_ * N_ * H_) / 4, 256, 0, stream>>>(NQKV);
    k_rms_rope_k<<<(B_ * N_ * H_) / 4, 256, 0, stream>>>(NQKV + SET, w_nestk, 1);

    k_flash<<<dim3(N_ / 64, B_ * H_, 1), 256, 0, stream>>>(
        NQKV, NQKV + SET, NVt, OUT2, NVt /*unused*/, DI_, 0, 0);

    k_transpose<<<dim3(32, 32), dim3(32, 8), 0, stream>>>(w_o, WOT, 1024, 1024);
    k_gemm_bt<true><<<dim3(32, 8), 256, 0, stream>>>(OUT2, WOT, (float*)d_out, 1024, 1024);
}

// Round 4
// 614.659 us; speedup vs baseline: 1.5470x; 1.3233x over previous
//
#include <hip/hip_runtime.h>
#include <hip/hip_bf16.h>
#include <stdint.h>

typedef unsigned short u16;
typedef __attribute__((ext_vector_type(8))) short short8;
typedef __attribute__((ext_vector_type(4))) float float4v;
typedef __attribute__((ext_vector_type(4))) unsigned int uint4v;

#define B_    2
#define N_    2048
#define DIM_  1024
#define H_    16
#define DH_   64
#define DI_   1024
#define EPS_  1.1920928955078125e-07f
#define LOG2_THETA 13.287712379549449f
#define SCL_  0.18033688011112042f   // (1/sqrt(64)) * log2(e)

__device__ __forceinline__ float bf2f(u16 u) {
    union { unsigned int i; float f; } v; v.i = ((unsigned int)u) << 16; return v.f;
}
__device__ __forceinline__ u16 f2bf(float f) {
    union { float f; unsigned int i; } v; v.f = f;
    unsigned int r = v.i + 0x7fff + ((v.i >> 16) & 1);
    return (u16)(r >> 16);
}

// ---------------- RMSNorm over DIM for fp32 tokens -> bf16 Xn ----------------
__global__ __launch_bounds__(256) void k_rmsnorm_x(
    const float* __restrict__ tok, const float* __restrict__ w, u16* __restrict__ xn) {
    int row = blockIdx.x;
    int t = threadIdx.x;
    const float* tr = tok + (size_t)row * DIM_;
    float vals[4];
    float ss = 0.f;
#pragma unroll
    for (int i = 0; i < 4; ++i) {
        float v = tr[t + i * 256];
        vals[i] = v; ss += v * v;
    }
#pragma unroll
    for (int o = 32; o; o >>= 1) ss += __shfl_xor(ss, o, 64);
    __shared__ float red[4];
    if ((t & 63) == 0) red[t >> 6] = ss;
    __syncthreads();
    ss = red[0] + red[1] + red[2] + red[3];
    float rs = rsqrtf(ss * (1.0f / DIM_) + EPS_);
    u16* orow = xn + (size_t)row * DIM_;
#pragma unroll
    for (int i = 0; i < 4; ++i) {
        int c = t + i * 256;
        orow[c] = f2bf(vals[i] * rs * w[c]);
    }
}

// ---------------- weight transpose (K x N fp32) -> (N x K bf16) ----------------
__global__ __launch_bounds__(256) void k_transpose(
    const float* __restrict__ src, u16* __restrict__ dst, int K, int N) {
    __shared__ float tile[32][33];
    int n0 = blockIdx.x * 32, k0 = blockIdx.y * 32;
    int tx = threadIdx.x, ty = threadIdx.y;  // 32 x 8
#pragma unroll
    for (int i = 0; i < 4; ++i)
        tile[ty + 8 * i][tx] = src[(size_t)(k0 + ty + 8 * i) * N + n0 + tx];
    __syncthreads();
#pragma unroll
    for (int i = 0; i < 4; ++i)
        dst[(size_t)(n0 + ty + 8 * i) * K + k0 + tx] = f2bf(tile[tx][ty + 8 * i]);
}

// ------- V transpose: VB token-major [B*N][3*1024] -> Vt [(s*B+b)*H+h][64][N] -------
__global__ __launch_bounds__(256) void k_transpose_v(
    const u16* __restrict__ VB, u16* __restrict__ Vt) {
    int y = blockIdx.y;                 // (s*B_+b)*H_+h
    int s = y >> 5;
    int b = (y >> 4) & 1;
    int h = y & 15;
    int n0 = blockIdx.x * 64;
    __shared__ u16 tile[64][72];
    int t = threadIdx.x;
#pragma unroll
    for (int i = 0; i < 2; ++i) {
        int idx = i * 256 + t;
        int row = idx >> 3, c = idx & 7;
        uint4v v = *(const uint4v*)(VB + ((size_t)(b * N_) + n0 + row) * 3072
                                        + s * 1024 + h * 64 + c * 8);
        *(uint4v*)&tile[row][c * 8] = v;
    }
    __syncthreads();
    u16* out = Vt + (size_t)y * 64 * N_;
#pragma unroll
    for (int i = 0; i < 2; ++i) {
        int idx = i * 256 + t;
        int dh = idx >> 3, c = idx & 7;
        union { uint4v v; u16 u[8]; } o;
#pragma unroll
        for (int j = 0; j < 8; ++j) o.u[j] = tile[c * 8 + j][dh];
        *(uint4v*)(out + (size_t)dh * N_ + n0 + c * 8) = o.v;
    }
}

// ---------------- GEMM: C[MxN] = A[MxK] * Bt[NxK]^T  (m97 structure) ----------------
template <bool OUT_F32>
__global__ __launch_bounds__(256) void k_gemm_bt(
    const u16* __restrict__ A, const u16* __restrict__ Bt, void* __restrict__ Cv,
    int K, int Ncols) {
    __shared__ u16 As[128 * 32];
    __shared__ u16 Bs[128 * 32];
    int m0 = blockIdx.x * 128, n0 = blockIdx.y * 128;
    int t = threadIdx.x;
    int w = t >> 6, lane = t & 63, ln = lane & 15, quad = lane >> 4;
    int wm = w & 1, wn = w >> 1;
    float4v acc[4][4] = {};
    const u16* Ag = A + (size_t)m0 * K;
    const u16* Bg = Bt + (size_t)n0 * K;
    for (int k0 = 0; k0 < K; k0 += 32) {
        __syncthreads();
#pragma unroll
        for (int i = 0; i < 2; ++i) {
            int idx = i * 256 + t;
            int row = idx >> 2, kb = idx & 3;
            const u16* ga = Ag + (size_t)row * K + k0 + kb * 8;
            const u16* gb = Bg + (size_t)row * K + k0 + kb * 8;
            __builtin_amdgcn_global_load_lds(
                (const __attribute__((address_space(1))) void*)ga,
                (__attribute__((address_space(3))) void*)(As + idx * 8), 16, 0, 0);
            __builtin_amdgcn_global_load_lds(
                (const __attribute__((address_space(1))) void*)gb,
                (__attribute__((address_space(3))) void*)(Bs + idx * 8), 16, 0, 0);
        }
        asm volatile("s_waitcnt vmcnt(0)" ::: "memory");
        __syncthreads();
        short8 af[4], bfr[4];
#pragma unroll
        for (int mt = 0; mt < 4; ++mt)
            af[mt] = *(const short8*)(As + (wm * 64 + mt * 16 + ln) * 32 + quad * 8);
#pragma unroll
        for (int nt = 0; nt < 4; ++nt)
            bfr[nt] = *(const short8*)(Bs + (wn * 64 + nt * 16 + ln) * 32 + quad * 8);
#pragma unroll
        for (int mt = 0; mt < 4; ++mt)
#pragma unroll
            for (int nt = 0; nt < 4; ++nt)
                acc[mt][nt] = __builtin_amdgcn_mfma_f32_16x16x32_bf16(
                    af[mt], bfr[nt], acc[mt][nt], 0, 0, 0);
    }
#pragma unroll
    for (int mt = 0; mt < 4; ++mt)
#pragma unroll
        for (int nt = 0; nt < 4; ++nt)
#pragma unroll
            for (int r = 0; r < 4; ++r) {
                int row = m0 + wm * 64 + mt * 16 + quad * 4 + r;
                int col = n0 + wn * 64 + nt * 16 + ln;
                if (OUT_F32)
                    ((float*)Cv)[(size_t)row * Ncols + col] = acc[mt][nt][r];
                else
                    ((u16*)Cv)[(size_t)row * Ncols + col] = f2bf(acc[mt][nt][r]);
            }
}

// ---------------- in-place RoPE on token-major [B*N][H*DH] (bf16) ----------------
__global__ __launch_bounds__(256) void k_rope(u16* __restrict__ buf) {
    int vid = blockIdx.x * 4 + (threadIdx.x >> 6);
    int lane = threadIdx.x & 63;
    int h = vid & (H_ - 1);
    int row = vid >> 4;
    int n = row & (N_ - 1);
    u16* p = buf + (size_t)row * DI_ + h * 64;
    float x = bf2f(p[lane]);
    float partner = __shfl_xor(x, 1, 64);
    float inv = exp2f(-(float)(lane & ~1) * (LOG2_THETA / 64.0f));
    float fr = (float)n * inv;
    float sv, cv;
    __sincosf(fr, &sv, &cv);
    float out = x * cv + ((lane & 1) ? partner : -partner) * sv;
    p[lane] = f2bf(out);
}

// ---------------- in-place RMSNorm(DH) + RoPE on K buffers (bf16, fp32 w) ----------------
__global__ __launch_bounds__(256) void k_rms_rope_k(
    u16* __restrict__ buf, const float* __restrict__ w, int nsets) {
    int vid = blockIdx.x * 4 + (threadIdx.x >> 6);
    int lane = threadIdx.x & 63;
    int h = vid % H_;
    int s = (vid / H_) % nsets;
    int row = vid / (H_ * nsets);
    int n = row & (N_ - 1);
    u16* p = buf + (size_t)row * (size_t)(nsets * DI_) + s * DI_ + h * 64;
    float x = bf2f(p[lane]);
    float ss = x * x;
#pragma unroll
    for (int o = 32; o; o >>= 1) ss += __shfl_xor(ss, o, 64);
    float rs = rsqrtf(ss * (1.0f / 64.0f) + EPS_);
    float xn = x * rs * w[s * 64 + lane];
    float partner = __shfl_xor(xn, 1, 64);
    float inv = exp2f(-(float)(lane & ~1) * (LOG2_THETA / 64.0f));
    float fr = (float)n * inv;
    float sv, cv;
    __sincosf(fr, &sv, &cv);
    float out = xn * cv + ((lane & 1) ? partner : -partner) * sv;
    p[lane] = f2bf(out);
}

// ---------------- flash attention v3: static max bound, deferred l-sum ----------------
// Keys are RMS-normalized (||k|| = 8 exactly), so score <= ||q_row||*8/sqrt(64) = ||q_row||.
// Fixed per-row max bound -> no online max, no alpha rescale, no per-tile reductions.
__global__ __launch_bounds__(256) void k_flash(
    const u16* __restrict__ Q, const u16* __restrict__ K, const u16* __restrict__ Vt,
    u16* __restrict__ O, u16* __restrict__ Ot,
    int kv_stride, int set_off, size_t o_set_stride) {
    int qt = gridDim.x - 1 - blockIdx.x;     // long blocks first
    int bh = blockIdx.y;
    int s = blockIdx.z;
    int b = bh >> 4, h = bh & 15;
    int t = threadIdx.x;
    int w = t >> 6, lane = t & 63, ln = lane & 15, quad = lane >> 4;
    int lnx = ln & 7;
    int q0 = qt * 64;

    const u16* Qb  = Q + ((size_t)b * N_) * DI_ + h * 64;
    const u16* Kb  = K + ((size_t)b * N_) * kv_stride + (size_t)s * set_off + h * 64;
    const u16* Vtb = Vt + (size_t)((s * B_ + b) * H_ + h) * (64 * (size_t)N_);

    // chunk-XOR swizzled tiles (slot (row,c) holds global chunk c^(row&7))
    __shared__ u16 Ks[2][64][64];
    __shared__ u16 Vs[2][64][64];
    __shared__ u16 Ps[4][16][64];   // swizzled: chunk cs stored at cs^(row&7)

    int qg = q0 + w * 16 + ln;
    short8 qf[2];
#pragma unroll
    for (int f = 0; f < 2; ++f)
        qf[f] = *(const short8*)(Qb + (size_t)qg * DI_ + f * 32 + quad * 8);

    // per-row score bound: m = ||q_row|| * 8 * SCL_ (keys have ||k||=8)
    float qn = 0.f;
#pragma unroll
    for (int f = 0; f < 2; ++f)
#pragma unroll
        for (int j = 0; j < 8; ++j) {
            float v = bf2f(((const u16*)&qf[f])[j]);
            qn += v * v;
        }
    qn += __shfl_xor(qn, 16, 64);
    qn += __shfl_xor(qn, 32, 64);   // lane (ln,*) now has ||q_ln||^2
    float mrow[4];
#pragma unroll
    for (int r = 0; r < 4; ++r) {
        float nq = __shfl(qn, quad * 4 + r, 64);
        mrow[r] = sqrtf(nq) * (8.0f * SCL_) * 1.03f + 1e-6f;
    }

    float lp[4] = {0.f, 0.f, 0.f, 0.f};
    float4v accO[4] = {};

    int ntiles = qt + 1;

    auto stage = [&](int kt0, int buf) {
        int k0 = kt0 * 64;
#pragma unroll
        for (int i = 0; i < 2; ++i) {
            int idx = i * 256 + t;
            int row = idx >> 3, c = idx & 7;
            int csrc = ((c ^ (row & 7)) * 8);
            const u16* ga = Kb + (size_t)(k0 + row) * kv_stride + csrc;
            __builtin_amdgcn_global_load_lds(
                (const __attribute__((address_space(1))) void*)ga,
                (__attribute__((address_space(3))) void*)&Ks[buf][row][c * 8], 16, 0, 0);
            const u16* gv = Vtb + (size_t)row * N_ + k0 + csrc;
            __builtin_amdgcn_global_load_lds(
                (const __attribute__((address_space(1))) void*)gv,
                (__attribute__((address_space(3))) void*)&Vs[buf][row][c * 8], 16, 0, 0);
        }
    };
    stage(0, 0);

    for (int kt0 = 0; kt0 < ntiles; ++kt0) {
        asm volatile("s_waitcnt vmcnt(0)" ::: "memory");
        __syncthreads();
        if (kt0 + 1 < ntiles) stage(kt0 + 1, (kt0 + 1) & 1);
        int buf = kt0 & 1;
        bool diag = (kt0 == ntiles - 1);

        // S = Q K^T, then p = exp2(S*SCL - m); accumulate l in-lane; stage P
#pragma unroll
        for (int kt = 0; kt < 4; ++kt) {
            const u16* krow = &Ks[buf][kt * 16 + ln][0];
            short8 kf0 = *(const short8*)(krow + ((quad ^ lnx) * 8));
            short8 kf1 = *(const short8*)(krow + (((4 + quad) ^ lnx) * 8));
            float4v sa = {};
            sa = __builtin_amdgcn_mfma_f32_16x16x32_bf16(qf[0], kf0, sa, 0, 0, 0);
            sa = __builtin_amdgcn_mfma_f32_16x16x32_bf16(qf[1], kf1, sa, 0, 0, 0);
#pragma unroll
            for (int r = 0; r < 4; ++r) {
                float arg = fmaf(sa[r], SCL_, -mrow[r]);
                if (diag) {
                    int kg = kt * 16 + ln;          // key offset within tile
                    int qr = w * 16 + quad * 4 + r; // q offset within tile
                    arg = (kg <= qr) ? arg : -100.f;
                }
                float pv = exp2f(arg);
                lp[r] += pv;
                int rowp = quad * 4 + r;
                int cs = (kt * 2 + (ln >> 3)) ^ (rowp & 7);
                Ps[w][rowp][cs * 8 + lnx] = f2bf(pv);
            }
        }
        asm volatile("s_waitcnt lgkmcnt(0)" ::: "memory");

        short8 pf0 = *(const short8*)&Ps[w][ln][(quad ^ lnx) * 8];
        short8 pf1 = *(const short8*)&Ps[w][ln][((4 + quad) ^ lnx) * 8];
#pragma unroll
        for (int dc = 0; dc < 4; ++dc) {
            const u16* vrow = &Vs[buf][dc * 16 + ln][0];
            short8 vf0 = *(const short8*)(vrow + ((quad ^ lnx) * 8));
            short8 vf1 = *(const short8*)(vrow + (((4 + quad) ^ lnx) * 8));
            accO[dc] = __builtin_amdgcn_mfma_f32_16x16x32_bf16(pf0, vf0, accO[dc], 0, 0, 0);
            accO[dc] = __builtin_amdgcn_mfma_f32_16x16x32_bf16(pf1, vf1, accO[dc], 0, 0, 0);
        }
    }

    // deferred l reduction (over the 16 ln lanes of each quad-group)
    float rinv[4];
#pragma unroll
    for (int r = 0; r < 4; ++r) {
        float l = lp[r];
#pragma unroll
        for (int o = 1; o < 16; o <<= 1) l += __shfl_xor(l, o, 64);
        rinv[r] = 1.0f / l;
    }

    if (s == 2) {
        u16* Otb = Ot + (size_t)(b * H_ + h) * (64 * (size_t)N_);
#pragma unroll
        for (int dc = 0; dc < 4; ++dc)
#pragma unroll
            for (int r = 0; r < 4; ++r) {
                int qr = q0 + w * 16 + quad * 4 + r;
                Otb[(size_t)(dc * 16 + ln) * N_ + qr] = f2bf(accO[dc][r] * rinv[r]);
            }
    } else {
        u16* Ob = O + (size_t)s * o_set_stride + ((size_t)b * N_) * DI_ + h * 64;
#pragma unroll
        for (int dc = 0; dc < 4; ++dc)
#pragma unroll
            for (int r = 0; r < 4; ++r) {
                int qr = q0 + w * 16 + quad * 4 + r;
                Ob[(size_t)qr * DI_ + dc * 16 + ln] = f2bf(accO[dc][r] * rinv[r]);
            }
    }
}

extern "C" void kernel_launch(void* const* d_in, const int* in_sizes, int n_in,
                              void* d_out, int out_size, void* d_ws, size_t ws_size,
                              hipStream_t stream) {
    const float* tok     = (const float*)d_in[0];
    const float* w_norm  = (const float*)d_in[1];
    const float* w_q     = (const float*)d_in[2];
    const float* w_k     = (const float*)d_in[3];
    const float* w_v     = (const float*)d_in[4];
    const float* w_keyn  = (const float*)d_in[5];
    const float* w_nestk = (const float*)d_in[6];
    const float* w_o     = (const float*)d_in[7];

    char* ws = (char*)d_ws;
    const size_t MB = 1024 * 1024;
    u16* XN   = (u16*)(ws + 0 * MB);
    u16* QB   = (u16*)(ws + 8 * MB);
    u16* KB   = (u16*)(ws + 16 * MB);    // 24 MB
    u16* VB   = (u16*)(ws + 40 * MB);    // 24 MB, dead after k_transpose_v
    u16* OUT2 = (u16*)(ws + 40 * MB);    // reuses VB
    u16* VtB  = (u16*)(ws + 64 * MB);    // 24 MB
    u16* WQT  = (u16*)(ws + 64 * MB);    // weights overlap VtB (dead before transpose_v)
    u16* WKT  = (u16*)(ws + 66 * MB);
    u16* WVT  = (u16*)(ws + 72 * MB);
    u16* NQKV = (u16*)(ws + 88 * MB);    // sets 0,1 token-major
    u16* NVt  = (u16*)(ws + 104 * MB);   // set 2 transposed
    u16* WOT  = (u16*)(ws + 0 * MB);     // reuses XN

    const size_t SET = (size_t)B_ * N_ * DI_;

    k_transpose<<<dim3(32, 32), dim3(32, 8), 0, stream>>>(w_q, WQT, 1024, 1024);
    k_transpose<<<dim3(96, 32), dim3(32, 8), 0, stream>>>(w_k, WKT, 1024, 3072);
    k_transpose<<<dim3(96, 32), dim3(32, 8), 0, stream>>>(w_v, WVT, 1024, 3072);

    k_rmsnorm_x<<<B_ * N_, 256, 0, stream>>>(tok, w_norm, XN);

    k_gemm_bt<false><<<dim3(32, 8),  256, 0, stream>>>(XN, WQT, QB, 1024, 1024);
    k_gemm_bt<false><<<dim3(32, 24), 256, 0, stream>>>(XN, WKT, KB, 1024, 3072);
    k_gemm_bt<false><<<dim3(32, 24), 256, 0, stream>>>(XN, WVT, VB, 1024, 3072);

    k_transpose_v<<<dim3(N_ / 64, 3 * B_ * H_), 256, 0, stream>>>(VB, VtB);

    k_rope<<<(B_ * N_ * H_) / 4, 256, 0, stream>>>(QB);
    k_rms_rope_k<<<(B_ * N_ * 3 * H_) / 4, 256, 0, stream>>>(KB, w_keyn, 3);

    k_flash<<<dim3(N_ / 64, B_ * H_, 3), 256, 0, stream>>>(
        QB, KB, VtB, NQKV, NVt, 3 * DI_, DI_, SET);

    k_rope<<<(B_ * N_ * H_) / 4, 256, 0, stream>>>(NQKV);
    k_rms_rope_k<<<(B_ * N_ * H_) / 4, 256, 0, stream>>>(NQKV + SET, w_nestk, 1);

    k_flash<<<dim3(N_ / 64, B_ * H_, 1), 256, 0, stream>>>(
        NQKV, NQKV + SET, NVt, OUT2, NVt /*unused*/, DI_, 0, 0);

    k_transpose<<<dim3(32, 32), dim3(32, 8), 0, stream>>>(w_o, WOT, 1024, 1024);
    k_gemm_bt<true><<<dim3(32, 8), 256, 0, stream>>>(OUT2, WOT, (float*)d_out, 1024, 1024);
}